// Round 1
// baseline (305.244 us; speedup 1.0000x reference)
//
#include <hip/hip_runtime.h>
#include <math.h>

// Problem constants: B=2, S=4096, D=512, H=4 (h-broadcast: out[b,h]=out[b,0])
#define SEQ 4096
#define DIM 512
#define NBATCH 2

typedef __bf16 bf16;
typedef __bf16 bf16x8 __attribute__((ext_vector_type(8)));
typedef __bf16 bf16x4 __attribute__((ext_vector_type(4)));
typedef float  f32x4  __attribute__((ext_vector_type(4)));

// async global->LDS, 16B per lane; LDS dst must be wave-uniform base (+lane*16 by HW)
#define GLOAD_LDS16(g, l)                                                              \
  __builtin_amdgcn_global_load_lds((__attribute__((address_space(1))) void*)(g),       \
                                   (__attribute__((address_space(3))) void*)(l), 16, 0, 0)

// ---------------------------------------------------------------------------
// Fused f32 -> bf16 casts: q,k,v (4,194,304 elems each), Wq,Wv (262,144 each)
// ---------------------------------------------------------------------------
__device__ __forceinline__ void cvt4(const float* __restrict__ s, bf16* __restrict__ d) {
  f32x4 x = *(const f32x4*)s;
  bf16x4 y;
  y[0] = (bf16)x[0]; y[1] = (bf16)x[1]; y[2] = (bf16)x[2]; y[3] = (bf16)x[3];
  *(bf16x4*)d = y;
}

__global__ __launch_bounds__(256)
void cast5(const float* __restrict__ q, const float* __restrict__ k,
           const float* __restrict__ v, const float* __restrict__ Wq,
           const float* __restrict__ Wv,
           bf16* __restrict__ qb, bf16* __restrict__ kb, bf16* __restrict__ vb,
           bf16* __restrict__ wqb, bf16* __restrict__ wvb) {
  const long NQ = (long)NBATCH * SEQ * DIM;  // 4,194,304
  const long NW = (long)DIM * DIM;           // 262,144
  long tid = blockIdx.x * 256L + threadIdx.x;
  long nth = gridDim.x * 256L;
  for (long i = tid * 4; i < NQ; i += nth * 4) {
    cvt4(q + i, qb + i);
    cvt4(k + i, kb + i);
    cvt4(v + i, vb + i);
  }
  for (long i = tid * 4; i < NW; i += nth * 4) {
    cvt4(Wq + i, wqb + i);
    cvt4(Wv + i, wvb + i);
  }
}

// ---------------------------------------------------------------------------
// GEMM (B^T input): C[M,N] = A[M,K] * Bt[N,K]^T, ldA=ldB=K, ldC=N.
// 128x128 tile, BK=32, 4 waves (2x2), per-wave 64x64 = 4x4 mfma frags.
// outMode 0: C bf16 row-major, C[r,c] = (acc+bias[c])*scale
// outMode 1: transposed per-batch store (V^T): row r -> (b=r>>12, s=r&4095),
//            C[b*DIM*SEQ + c*SEQ + s]
// ---------------------------------------------------------------------------
__global__ __launch_bounds__(256, 2)
void gemm_bt(const bf16* __restrict__ A, const bf16* __restrict__ Bt,
             bf16* __restrict__ C, const float* __restrict__ bias,
             float scale, int N, int K,
             long sA, long sB, long sC, int outMode) {
  __shared__ __align__(16) bf16 lA[128 * 32];
  __shared__ __align__(16) bf16 lB[128 * 32];
  const int t = threadIdx.x;
  const int z = blockIdx.z;
  A += z * sA; Bt += z * sB; C += z * sC;
  const long m0 = (long)blockIdx.x * 128;
  const long n0 = (long)blockIdx.y * 128;
  const int l = t & 63, w = t >> 6;
  const int wr = (w >> 1) * 64, wc = (w & 1) * 64;
  const int lr = l & 15, lg = l >> 4;

  // staging: 2 chunks of 16B per thread per matrix; chunk c -> row c/4, kcol (c%4)*8
  const int c0 = t, c1 = t + 256;
  const int r0 = c0 >> 2, kc0 = (c0 & 3) * 8;
  const int r1 = c1 >> 2, kc1 = (c1 & 3) * 8;
  bf16* lA0 = lA + (w * 64) * 8;          // wave-uniform LDS dst (HW adds lane*16B)
  bf16* lA1 = lA + (256 + w * 64) * 8;
  bf16* lB0 = lB + (w * 64) * 8;
  bf16* lB1 = lB + (256 + w * 64) * 8;
  const bf16* gA0 = A + (m0 + r0) * (long)K + kc0;
  const bf16* gA1 = A + (m0 + r1) * (long)K + kc1;
  const bf16* gB0 = Bt + (n0 + r0) * (long)K + kc0;
  const bf16* gB1 = Bt + (n0 + r1) * (long)K + kc1;

  f32x4 acc[4][4] = {};
  for (int kk = 0; kk < K; kk += 32) {
    GLOAD_LDS16(gA0 + kk, lA0);
    GLOAD_LDS16(gA1 + kk, lA1);
    GLOAD_LDS16(gB0 + kk, lB0);
    GLOAD_LDS16(gB1 + kk, lB1);
    __syncthreads();
    bf16x8 af[4], bfr[4];
#pragma unroll
    for (int m = 0; m < 4; ++m)
      af[m] = *(const bf16x8*)(lA + (wr + m * 16 + lr) * 32 + lg * 8);
#pragma unroll
    for (int n = 0; n < 4; ++n)
      bfr[n] = *(const bf16x8*)(lB + (wc + n * 16 + lr) * 32 + lg * 8);
#pragma unroll
    for (int m = 0; m < 4; ++m)
#pragma unroll
      for (int n = 0; n < 4; ++n)
        acc[m][n] = __builtin_amdgcn_mfma_f32_16x16x32_bf16(af[m], bfr[n], acc[m][n], 0, 0, 0);
    __syncthreads();
  }

  // epilogue: C/D layout col=lane&15, row=(lane>>4)*4+reg
#pragma unroll
  for (int n = 0; n < 4; ++n) {
    const long col = n0 + wc + n * 16 + lr;
    const float bcol = bias ? bias[col] : 0.0f;
#pragma unroll
    for (int m = 0; m < 4; ++m) {
      const long rowb = m0 + wr + m * 16 + lg * 4;
#pragma unroll
      for (int r = 0; r < 4; ++r) {
        float vv = (acc[m][n][r] + bcol) * scale;
        bf16 o = (bf16)vv;
        if (outMode == 0) {
          C[(rowb + r) * (long)N + col] = o;
        } else {
          long gr = rowb + r;                 // global row over both batches
          long bb = gr >> 12, ss = gr & 4095; // b, s
          C[bb * (long)(DIM * SEQ) + col * (long)SEQ + ss] = o;
        }
      }
    }
  }
}

// ---------------------------------------------------------------------------
// Row softmax, in place, bf16. One block per row (4096 cols), 256 thr x 16 elems.
// ---------------------------------------------------------------------------
__global__ __launch_bounds__(256)
void softmax_rows(bf16* __restrict__ Sb, long zstride) {
  bf16* row = Sb + (long)blockIdx.y * zstride + (long)blockIdx.x * SEQ;
  const int t = threadIdx.x;
  float x[16];
  bf16x8 v0 = *(const bf16x8*)(row + t * 16);
  bf16x8 v1 = *(const bf16x8*)(row + t * 16 + 8);
#pragma unroll
  for (int i = 0; i < 8; ++i) { x[i] = (float)v0[i]; x[8 + i] = (float)v1[i]; }

  float mx = x[0];
#pragma unroll
  for (int i = 1; i < 16; ++i) mx = fmaxf(mx, x[i]);
  for (int o = 32; o; o >>= 1) mx = fmaxf(mx, __shfl_xor(mx, o));
  __shared__ float red[8];
  const int w = t >> 6;
  if ((t & 63) == 0) red[w] = mx;
  __syncthreads();
  mx = fmaxf(fmaxf(red[0], red[1]), fmaxf(red[2], red[3]));

  float sum = 0.0f;
#pragma unroll
  for (int i = 0; i < 16; ++i) { x[i] = __expf(x[i] - mx); sum += x[i]; }
  for (int o = 32; o; o >>= 1) sum += __shfl_xor(sum, o);
  if ((t & 63) == 0) red[4 + w] = sum;
  __syncthreads();
  sum = red[4] + red[5] + red[6] + red[7];
  float inv = 1.0f / sum;

  bf16x8 o0, o1;
#pragma unroll
  for (int i = 0; i < 8; ++i) {
    o0[i] = (bf16)(x[i] * inv);
    o1[i] = (bf16)(x[8 + i] * inv);
  }
  *(bf16x8*)(row + t * 16) = o0;
  *(bf16x8*)(row + t * 16 + 8) = o1;
}

// ---------------------------------------------------------------------------
// PV GEMM: O[s,d] = sum_t P[s,t] * Vt[d,t];  M=4096, N=512, K=4096.
// BM=128, BN=64, BK=32; 4 waves 2x2, per-wave 64x32 = 4x2 frags.
// Epilogue writes f32 to out[b,h,s,d] for h=0..3 (broadcast heads).
// ---------------------------------------------------------------------------
__global__ __launch_bounds__(256, 2)
void gemm_pv(const bf16* __restrict__ P, const bf16* __restrict__ Vt,
             float* __restrict__ out, long sP, long sV, long sO) {
  __shared__ __align__(16) bf16 lA[128 * 32];
  __shared__ __align__(16) bf16 lB[64 * 32];
  const int t = threadIdx.x;
  const int z = blockIdx.z;
  P += z * sP; Vt += z * sV; out += z * sO;
  const long m0 = (long)blockIdx.x * 128;
  const long n0 = (long)blockIdx.y * 64;
  const int l = t & 63, w = t >> 6;
  const int wr = (w >> 1) * 64, wc = (w & 1) * 32;
  const int lr = l & 15, lg = l >> 4;
  const int K = SEQ;

  const int c0 = t, c1 = t + 256;
  const int r0 = c0 >> 2, kc0 = (c0 & 3) * 8;
  const int r1 = c1 >> 2, kc1 = (c1 & 3) * 8;
  bf16* lA0 = lA + (w * 64) * 8;
  bf16* lA1 = lA + (256 + w * 64) * 8;
  bf16* lB0 = lB + (w * 64) * 8;
  const bf16* gA0 = P + (m0 + r0) * (long)K + kc0;
  const bf16* gA1 = P + (m0 + r1) * (long)K + kc1;
  const bf16* gB0 = Vt + (n0 + r0) * (long)K + kc0;  // r0 in 0..63 for c0<256

  f32x4 acc[4][2] = {};
  for (int kk = 0; kk < K; kk += 32) {
    GLOAD_LDS16(gA0 + kk, lA0);
    GLOAD_LDS16(gA1 + kk, lA1);
    GLOAD_LDS16(gB0 + kk, lB0);
    __syncthreads();
    bf16x8 af[4], bfr[2];
#pragma unroll
    for (int m = 0; m < 4; ++m)
      af[m] = *(const bf16x8*)(lA + (wr + m * 16 + lr) * 32 + lg * 8);
#pragma unroll
    for (int n = 0; n < 2; ++n)
      bfr[n] = *(const bf16x8*)(lB + (wc + n * 16 + lr) * 32 + lg * 8);
#pragma unroll
    for (int m = 0; m < 4; ++m)
#pragma unroll
      for (int n = 0; n < 2; ++n)
        acc[m][n] = __builtin_amdgcn_mfma_f32_16x16x32_bf16(af[m], bfr[n], acc[m][n], 0, 0, 0);
    __syncthreads();
  }

#pragma unroll
  for (int n = 0; n < 2; ++n) {
    const long col = n0 + wc + n * 16 + lr;  // d
#pragma unroll
    for (int m = 0; m < 4; ++m) {
      const long rowb = m0 + wr + m * 16 + lg * 4;  // s
#pragma unroll
      for (int r = 0; r < 4; ++r) {
        float vv = acc[m][n][r];
        float* o0 = out + (rowb + r) * (long)DIM + col;
        o0[0] = vv;                       // h=0
        o0[1L * SEQ * DIM] = vv;          // h=1
        o0[2L * SEQ * DIM] = vv;          // h=2
        o0[3L * SEQ * DIM] = vv;          // h=3
      }
    }
  }
}

// ---------------------------------------------------------------------------
// Host launch
// ---------------------------------------------------------------------------
extern "C" void kernel_launch(void* const* d_in, const int* in_sizes, int n_in,
                              void* d_out, int out_size, void* d_ws, size_t ws_size,
                              hipStream_t stream) {
  const float* q  = (const float*)d_in[0];
  const float* k  = (const float*)d_in[1];
  const float* v  = (const float*)d_in[2];
  const float* Wq = (const float*)d_in[3];
  const float* bq = (const float*)d_in[4];
  const float* Wv = (const float*)d_in[5];
  const float* bv = (const float*)d_in[6];
  float* outp = (float*)d_out;

  const long NQ = (long)NBATCH * SEQ * DIM;  // 4,194,304 elems
  const long NW = (long)DIM * DIM;           // 262,144
  bf16* Qbf = (bf16*)d_ws;       // scaled Q projection (bf16), [B*S, D]
  bf16* Kbf = Qbf + NQ;          // k cast (bf16), [B*S, D]
  bf16* Vt  = Kbf + NQ;          // V projection transposed, [B, D, S]
  bf16* Wqb = Vt + NQ;
  bf16* Wvb = Wqb + NW;
  bf16* Sbuf = Wvb + NW;         // scores/probs, bf16
  const size_t baseBytes = (size_t)((char*)Sbuf - (char*)d_ws);   // 26,214,400
  const bool batched = ws_size >= baseBytes + 2ULL * SEQ * SEQ * 2; // need +64 MiB
  // q/v bf16 temporaries live inside the (not yet used) S region
  bf16* qb = Sbuf;
  bf16* vb = Sbuf + NQ;

  const float QSCALE = 0.04419417382415922f;  // 1/sqrt(512)

  cast5<<<dim3(2048), dim3(256), 0, stream>>>(q, k, v, Wq, Wv, qb, Kbf, vb, Wqb, Wvb);
  // Q = (q@Wq^T + bq)/sqrt(D)  -> Qbf
  gemm_bt<<<dim3(64, 4, 1), dim3(256), 0, stream>>>(qb, Wqb, Qbf, bq, QSCALE,
                                                    512, 512, 0, 0, 0, 0);
  // V = v@Wv^T + bv -> Vt (transposed per batch)
  gemm_bt<<<dim3(64, 4, 1), dim3(256), 0, stream>>>(vb, Wvb, Vt, bv, 1.0f,
                                                    512, 512, 0, 0, 0, 1);
  const long sQK = (long)SEQ * DIM;      // 2,097,152
  const long sS  = (long)SEQ * SEQ;      // 16,777,216
  const long sO  = 4L * SEQ * DIM;       // 8,388,608 (H*S*D)
  if (batched) {
    gemm_bt<<<dim3(32, 32, 2), dim3(256), 0, stream>>>(Qbf, Kbf, Sbuf, nullptr, 1.0f,
                                                       4096, 512, sQK, sQK, sS, 0);
    softmax_rows<<<dim3(4096, 2), dim3(256), 0, stream>>>(Sbuf, sS);
    gemm_pv<<<dim3(32, 8, 2), dim3(256), 0, stream>>>(Sbuf, Vt, outp, sS, sQK, sO);
  } else {
    for (int b = 0; b < 2; ++b) {
      gemm_bt<<<dim3(32, 32, 1), dim3(256), 0, stream>>>(Qbf + b * sQK, Kbf + b * sQK,
                                                         Sbuf, nullptr, 1.0f,
                                                         4096, 512, 0, 0, 0, 0);
      softmax_rows<<<dim3(4096, 1), dim3(256), 0, stream>>>(Sbuf, 0);
      gemm_pv<<<dim3(32, 8, 1), dim3(256), 0, stream>>>(Sbuf, Vt + b * sQK,
                                                        outp + b * sO, 0, 0, 0);
    }
  }
}

// Round 2
// 271.681 us; speedup vs baseline: 1.1235x; 1.1235x over previous
//
#include <hip/hip_runtime.h>
#include <math.h>

// Problem constants: B=2, S=4096, D=512, H=4 (h-broadcast: out[b,h]=out[b,0])
#define SEQ 4096
#define DIM 512
#define NBATCH 2

typedef __bf16 bf16;
typedef __bf16 bf16x8 __attribute__((ext_vector_type(8)));
typedef __bf16 bf16x4 __attribute__((ext_vector_type(4)));
typedef float  f32x4  __attribute__((ext_vector_type(4)));

// async global->LDS, 16B per lane; LDS dst must be wave-uniform base (+lane*16 by HW)
#define GLOAD_LDS16(g, l)                                                              \
  __builtin_amdgcn_global_load_lds((__attribute__((address_space(1))) void*)(g),       \
                                   (__attribute__((address_space(3))) void*)(l), 16, 0, 0)

// ---------------------------------------------------------------------------
// Fused f32 -> bf16 casts: q,k,v (4,194,304 elems each), Wq,Wv (262,144 each)
// ---------------------------------------------------------------------------
__device__ __forceinline__ void cvt4(const float* __restrict__ s, bf16* __restrict__ d) {
  f32x4 x = *(const f32x4*)s;
  bf16x4 y;
  y[0] = (bf16)x[0]; y[1] = (bf16)x[1]; y[2] = (bf16)x[2]; y[3] = (bf16)x[3];
  *(bf16x4*)d = y;
}

__global__ __launch_bounds__(256)
void cast5(const float* __restrict__ q, const float* __restrict__ k,
           const float* __restrict__ v, const float* __restrict__ Wq,
           const float* __restrict__ Wv,
           bf16* __restrict__ qb, bf16* __restrict__ kb, bf16* __restrict__ vb,
           bf16* __restrict__ wqb, bf16* __restrict__ wvb) {
  const long NQ = (long)NBATCH * SEQ * DIM;  // 4,194,304
  const long NW = (long)DIM * DIM;           // 262,144
  long tid = blockIdx.x * 256L + threadIdx.x;
  long nth = gridDim.x * 256L;
  for (long i = tid * 4; i < NQ; i += nth * 4) {
    cvt4(q + i, qb + i);
    cvt4(k + i, kb + i);
    cvt4(v + i, vb + i);
  }
  for (long i = tid * 4; i < NW; i += nth * 4) {
    cvt4(Wq + i, wqb + i);
    cvt4(Wv + i, wvb + i);
  }
}

// ---------------------------------------------------------------------------
// Projection GEMM (B^T input), BK=32 m97 structure — kept for the two small
// 512x512 projections. C[M,N] = A[M,K]*Bt[N,K]^T.
// outMode 0: bf16 row-major (acc+bias)*scale; outMode 1: per-batch transposed
// store (V^T): global row r -> C[(r>>12)*D*S + col*S + (r&4095)]
// ---------------------------------------------------------------------------
__global__ __launch_bounds__(256, 2)
void gemm_bt(const bf16* __restrict__ A, const bf16* __restrict__ Bt,
             bf16* __restrict__ C, const float* __restrict__ bias,
             float scale, int N, int K,
             long sA, long sB, long sC, int outMode) {
  __shared__ __align__(16) bf16 lA[128 * 32];
  __shared__ __align__(16) bf16 lB[128 * 32];
  const int t = threadIdx.x;
  const int z = blockIdx.z;
  A += z * sA; Bt += z * sB; C += z * sC;
  const long m0 = (long)blockIdx.x * 128;
  const long n0 = (long)blockIdx.y * 128;
  const int l = t & 63, w = t >> 6;
  const int wr = (w >> 1) * 64, wc = (w & 1) * 64;
  const int lr = l & 15, lg = l >> 4;

  const int c0 = t, c1 = t + 256;
  const int r0 = c0 >> 2, kc0 = (c0 & 3) * 8;
  const int r1 = c1 >> 2, kc1 = (c1 & 3) * 8;
  bf16* lA0 = lA + (w * 64) * 8;
  bf16* lA1 = lA + (256 + w * 64) * 8;
  bf16* lB0 = lB + (w * 64) * 8;
  bf16* lB1 = lB + (256 + w * 64) * 8;
  const bf16* gA0 = A + (m0 + r0) * (long)K + kc0;
  const bf16* gA1 = A + (m0 + r1) * (long)K + kc1;
  const bf16* gB0 = Bt + (n0 + r0) * (long)K + kc0;
  const bf16* gB1 = Bt + (n0 + r1) * (long)K + kc1;

  f32x4 acc[4][4] = {};
  for (int kk = 0; kk < K; kk += 32) {
    GLOAD_LDS16(gA0 + kk, lA0);
    GLOAD_LDS16(gA1 + kk, lA1);
    GLOAD_LDS16(gB0 + kk, lB0);
    GLOAD_LDS16(gB1 + kk, lB1);
    __syncthreads();
    bf16x8 af[4], bfr[4];
#pragma unroll
    for (int m = 0; m < 4; ++m)
      af[m] = *(const bf16x8*)(lA + (wr + m * 16 + lr) * 32 + lg * 8);
#pragma unroll
    for (int n = 0; n < 4; ++n)
      bfr[n] = *(const bf16x8*)(lB + (wc + n * 16 + lr) * 32 + lg * 8);
#pragma unroll
    for (int m = 0; m < 4; ++m)
#pragma unroll
      for (int n = 0; n < 4; ++n)
        acc[m][n] = __builtin_amdgcn_mfma_f32_16x16x32_bf16(af[m], bfr[n], acc[m][n], 0, 0, 0);
    __syncthreads();
  }

#pragma unroll
  for (int n = 0; n < 4; ++n) {
    const long col = n0 + wc + n * 16 + lr;
    const float bcol = bias ? bias[col] : 0.0f;
#pragma unroll
    for (int m = 0; m < 4; ++m) {
      const long rowb = m0 + wr + m * 16 + lg * 4;
#pragma unroll
      for (int r = 0; r < 4; ++r) {
        float vv = (acc[m][n][r] + bcol) * scale;
        bf16 o = (bf16)vv;
        if (outMode == 0) {
          C[(rowb + r) * (long)N + col] = o;
        } else {
          long gr = rowb + r;
          long bb = gr >> 12, ss = gr & 4095;
          C[bb * (long)(DIM * SEQ) + col * (long)SEQ + ss] = o;
        }
      }
    }
  }
}

// ---------------------------------------------------------------------------
// Main GEMM template: BM=128, BK=64, BN in {64,128}. 4 waves (2x2).
// Both-sides XOR swizzle (rule #21): LDS dest linear (global_load_lds), the
// 16B-chunk column index is XOR'd with (row&7) on the GLOBAL source and the
// same XOR applied on ds_read -> each 16-lane read phase covers all 32 banks
// exactly 2x (conflict-free per m136).
// OUT 0: bf16 C row-major, *scale.  OUT 2: f32 out with 4 h-broadcast copies.
// ---------------------------------------------------------------------------
template <int BN, int OUT>
__global__ __launch_bounds__(256, (BN == 128 ? 2 : 3))
void gemm64(const bf16* __restrict__ A, const bf16* __restrict__ Bt,
            void* __restrict__ Cv, float scale, int N, int K,
            long sA, long sB, long sC) {
  __shared__ __align__(16) bf16 lA[128 * 64];
  __shared__ __align__(16) bf16 lB[BN * 64];
  constexpr int NFR = BN / 32;  // n-frags per wave
  constexpr int BI = BN / 32;   // B staging insts (BN*8 chunks / 256 thr)
  const int t = threadIdx.x;
  const int z = blockIdx.z;
  A += z * sA; Bt += z * sB;
  const long m0 = (long)blockIdx.x * 128;
  const long n0 = (long)blockIdx.y * BN;
  const int l = t & 63, w = t >> 6;
  const int wr = (w >> 1) * 64, wc = (w & 1) * (BN / 2);
  const int lr = l & 15, lg = l >> 4;

  // staging: slot s (16B units) holds row=s>>3, k-chunk (s&7)^(row&7)
  const bf16* gA[4];
  const bf16* gB[BI];
#pragma unroll
  for (int i = 0; i < 4; ++i) {
    int s = i * 256 + t, row = s >> 3, kc = (s & 7) ^ (row & 7);
    gA[i] = A + (m0 + row) * (long)K + kc * 8;
  }
#pragma unroll
  for (int i = 0; i < BI; ++i) {
    int s = i * 256 + t, row = s >> 3, kc = (s & 7) ^ (row & 7);
    gB[i] = Bt + (n0 + row) * (long)K + kc * 8;
  }

  // ds_read elem offsets: row*64 + ((ks*4+lg)^(row&7))*8 ; row&7 == lr&7
  int offA[4][2], offB[NFR][2];
#pragma unroll
  for (int m = 0; m < 4; ++m)
#pragma unroll
    for (int ks = 0; ks < 2; ++ks)
      offA[m][ks] = (wr + m * 16 + lr) * 64 + (((ks * 4 + lg) ^ (lr & 7)) * 8);
#pragma unroll
  for (int n = 0; n < NFR; ++n)
#pragma unroll
    for (int ks = 0; ks < 2; ++ks)
      offB[n][ks] = (wc + n * 16 + lr) * 64 + (((ks * 4 + lg) ^ (lr & 7)) * 8);

  f32x4 acc[4][NFR] = {};
  for (int kk = 0; kk < K; kk += 64) {
#pragma unroll
    for (int i = 0; i < 4; ++i)
      GLOAD_LDS16(gA[i] + kk, lA + (i * 256 + w * 64) * 8);
#pragma unroll
    for (int i = 0; i < BI; ++i)
      GLOAD_LDS16(gB[i] + kk, lB + (i * 256 + w * 64) * 8);
    __syncthreads();
#pragma unroll
    for (int ks = 0; ks < 2; ++ks) {
      bf16x8 af[4], bfn[NFR];
#pragma unroll
      for (int m = 0; m < 4; ++m) af[m] = *(const bf16x8*)(lA + offA[m][ks]);
#pragma unroll
      for (int n = 0; n < NFR; ++n) bfn[n] = *(const bf16x8*)(lB + offB[n][ks]);
#pragma unroll
      for (int m = 0; m < 4; ++m)
#pragma unroll
        for (int n = 0; n < NFR; ++n)
          acc[m][n] = __builtin_amdgcn_mfma_f32_16x16x32_bf16(af[m], bfn[n], acc[m][n], 0, 0, 0);
    }
    __syncthreads();
  }

  if constexpr (OUT == 0) {
    bf16* C = (bf16*)Cv + z * sC;
#pragma unroll
    for (int n = 0; n < NFR; ++n) {
      const long col = n0 + wc + n * 16 + lr;
#pragma unroll
      for (int m = 0; m < 4; ++m) {
        const long rowb = m0 + wr + m * 16 + lg * 4;
#pragma unroll
        for (int r = 0; r < 4; ++r)
          C[(rowb + r) * (long)N + col] = (bf16)(acc[m][n][r] * scale);
      }
    }
  } else {
    float* o = (float*)Cv + z * sC;
#pragma unroll
    for (int n = 0; n < NFR; ++n) {
      const long col = n0 + wc + n * 16 + lr;  // d
#pragma unroll
      for (int m = 0; m < 4; ++m) {
        const long rowb = m0 + wr + m * 16 + lg * 4;  // s
#pragma unroll
        for (int r = 0; r < 4; ++r) {
          float vv = acc[m][n][r];
          float* p = o + (rowb + r) * (long)DIM + col;
          p[0] = vv;
          p[1L * SEQ * DIM] = vv;
          p[2L * SEQ * DIM] = vv;
          p[3L * SEQ * DIM] = vv;
        }
      }
    }
  }
}

// ---------------------------------------------------------------------------
// Row softmax, in place, bf16. One block per row (4096 cols), 256 thr x 16.
// ---------------------------------------------------------------------------
__global__ __launch_bounds__(256)
void softmax_rows(bf16* __restrict__ Sb, long zstride) {
  bf16* row = Sb + (long)blockIdx.y * zstride + (long)blockIdx.x * SEQ;
  const int t = threadIdx.x;
  float x[16];
  bf16x8 v0 = *(const bf16x8*)(row + t * 16);
  bf16x8 v1 = *(const bf16x8*)(row + t * 16 + 8);
#pragma unroll
  for (int i = 0; i < 8; ++i) { x[i] = (float)v0[i]; x[8 + i] = (float)v1[i]; }

  float mx = x[0];
#pragma unroll
  for (int i = 1; i < 16; ++i) mx = fmaxf(mx, x[i]);
  for (int o = 32; o; o >>= 1) mx = fmaxf(mx, __shfl_xor(mx, o));
  __shared__ float red[8];
  const int w = t >> 6;
  if ((t & 63) == 0) red[w] = mx;
  __syncthreads();
  mx = fmaxf(fmaxf(red[0], red[1]), fmaxf(red[2], red[3]));

  float sum = 0.0f;
#pragma unroll
  for (int i = 0; i < 16; ++i) { x[i] = __expf(x[i] - mx); sum += x[i]; }
  for (int o = 32; o; o >>= 1) sum += __shfl_xor(sum, o);
  if ((t & 63) == 0) red[4 + w] = sum;
  __syncthreads();
  sum = red[4] + red[5] + red[6] + red[7];
  float inv = 1.0f / sum;

  bf16x8 o0, o1;
#pragma unroll
  for (int i = 0; i < 8; ++i) {
    o0[i] = (bf16)(x[i] * inv);
    o1[i] = (bf16)(x[8 + i] * inv);
  }
  *(bf16x8*)(row + t * 16) = o0;
  *(bf16x8*)(row + t * 16 + 8) = o1;
}

// ---------------------------------------------------------------------------
// Host launch
// ---------------------------------------------------------------------------
extern "C" void kernel_launch(void* const* d_in, const int* in_sizes, int n_in,
                              void* d_out, int out_size, void* d_ws, size_t ws_size,
                              hipStream_t stream) {
  const float* q  = (const float*)d_in[0];
  const float* k  = (const float*)d_in[1];
  const float* v  = (const float*)d_in[2];
  const float* Wq = (const float*)d_in[3];
  const float* bq = (const float*)d_in[4];
  const float* Wv = (const float*)d_in[5];
  const float* bv = (const float*)d_in[6];
  float* outp = (float*)d_out;

  const long NQ = (long)NBATCH * SEQ * DIM;  // 4,194,304 elems
  const long NW = (long)DIM * DIM;           // 262,144
  bf16* Qbf = (bf16*)d_ws;       // scaled Q projection (bf16), [B*S, D]
  bf16* Kbf = Qbf + NQ;          // k cast (bf16), [B*S, D]
  bf16* Vt  = Kbf + NQ;          // V projection transposed, [B, D, S]
  bf16* Wqb = Vt + NQ;
  bf16* Wvb = Wqb + NW;
  bf16* Sbuf = Wvb + NW;         // scores/probs, bf16
  const size_t baseBytes = (size_t)((char*)Sbuf - (char*)d_ws);     // 26,214,400
  const bool batched = ws_size >= baseBytes + 2ULL * SEQ * SEQ * 2; // need +64 MiB
  bf16* qb = Sbuf;
  bf16* vb = Sbuf + NQ;

  const float QSCALE = 0.04419417382415922f;  // 1/sqrt(512)

  cast5<<<dim3(2048), dim3(256), 0, stream>>>(q, k, v, Wq, Wv, qb, Kbf, vb, Wqb, Wvb);
  gemm_bt<<<dim3(64, 4, 1), dim3(256), 0, stream>>>(qb, Wqb, Qbf, bq, QSCALE,
                                                    512, 512, 0, 0, 0, 0);
  gemm_bt<<<dim3(64, 4, 1), dim3(256), 0, stream>>>(vb, Wvb, Vt, bv, 1.0f,
                                                    512, 512, 0, 0, 0, 1);
  const long sQK = (long)SEQ * DIM;      // 2,097,152
  const long sS  = (long)SEQ * SEQ;      // 16,777,216
  const long sO  = 4L * SEQ * DIM;       // 8,388,608 (H*S*D)
  if (batched) {
    gemm64<128, 0><<<dim3(32, 32, 2), dim3(256), 0, stream>>>(
        Qbf, Kbf, Sbuf, 1.0f, 4096, 512, sQK, sQK, sS);
    softmax_rows<<<dim3(4096, 2), dim3(256), 0, stream>>>(Sbuf, sS);
    gemm64<64, 2><<<dim3(32, 8, 2), dim3(256), 0, stream>>>(
        Sbuf, Vt, outp, 1.0f, 512, 4096, sS, sQK, sO);
  } else {
    for (int b = 0; b < 2; ++b) {
      gemm64<128, 0><<<dim3(32, 32, 1), dim3(256), 0, stream>>>(
          Qbf + b * sQK, Kbf + b * sQK, Sbuf, 1.0f, 4096, 512, 0, 0, 0);
      softmax_rows<<<dim3(4096, 1), dim3(256), 0, stream>>>(Sbuf, 0);
      gemm64<64, 2><<<dim3(32, 8, 1), dim3(256), 0, stream>>>(
          Sbuf, Vt + b * sQK, outp + b * sO, 1.0f, 512, 4096, 0, 0, 0);
    }
  }
}

// Round 3
// 256.096 us; speedup vs baseline: 1.1919x; 1.0609x over previous
//
#include <hip/hip_runtime.h>
#include <math.h>

// Problem: B=2, S=4096, D=512, H=4 (h-broadcast: out[b,h]=out[b,0])
// Pipeline: cast -> Qproj,Vproj -> S-GEMM(+exp,+rowsum) -> PV(+1/rowsum, x4 h)
#define SEQ 4096
#define DIM 512
#define NBATCH 2

typedef __bf16 bf16;
typedef __bf16 bf16x8 __attribute__((ext_vector_type(8)));
typedef __bf16 bf16x4 __attribute__((ext_vector_type(4)));
typedef float  f32x4  __attribute__((ext_vector_type(4)));

// async global->LDS, 16B per lane; LDS dst is wave-uniform base (+lane*16 by HW)
#define GLOAD_LDS16(g, l)                                                              \
  __builtin_amdgcn_global_load_lds((__attribute__((address_space(1))) void*)(g),       \
                                   (__attribute__((address_space(3))) void*)(l), 16, 0, 0)

// ---------------------------------------------------------------------------
// Fused f32 -> bf16 casts
// ---------------------------------------------------------------------------
__device__ __forceinline__ void cvt4(const float* __restrict__ s, bf16* __restrict__ d) {
  f32x4 x = *(const f32x4*)s;
  bf16x4 y;
  y[0] = (bf16)x[0]; y[1] = (bf16)x[1]; y[2] = (bf16)x[2]; y[3] = (bf16)x[3];
  *(bf16x4*)d = y;
}

__global__ __launch_bounds__(256)
void cast5(const float* __restrict__ q, const float* __restrict__ k,
           const float* __restrict__ v, const float* __restrict__ Wq,
           const float* __restrict__ Wv,
           bf16* __restrict__ qb, bf16* __restrict__ kb, bf16* __restrict__ vb,
           bf16* __restrict__ wqb, bf16* __restrict__ wvb) {
  const long NQ = (long)NBATCH * SEQ * DIM;
  const long NW = (long)DIM * DIM;
  long tid = blockIdx.x * 256L + threadIdx.x;
  long nth = gridDim.x * 256L;
  for (long i = tid * 4; i < NQ; i += nth * 4) {
    cvt4(q + i, qb + i);
    cvt4(k + i, kb + i);
    cvt4(v + i, vb + i);
  }
  for (long i = tid * 4; i < NW; i += nth * 4) {
    cvt4(Wq + i, wqb + i);
    cvt4(Wv + i, wvb + i);
  }
}

__global__ __launch_bounds__(256)
void zero_f32(float* __restrict__ p, int n) {
  int i = blockIdx.x * 256 + threadIdx.x;
  if (i < n) p[i] = 0.0f;
}

// ---------------------------------------------------------------------------
// Projection GEMM (B^T input), BK=32 — the two small 512x512 projections.
// outMode 0: bf16 row-major (acc+bias)*scale; outMode 1: transposed store V^T
// ---------------------------------------------------------------------------
__global__ __launch_bounds__(256, 2)
void gemm_bt(const bf16* __restrict__ A, const bf16* __restrict__ Bt,
             bf16* __restrict__ C, const float* __restrict__ bias,
             float scale, int N, int K,
             long sA, long sB, long sC, int outMode) {
  __shared__ __align__(16) bf16 lA[128 * 32];
  __shared__ __align__(16) bf16 lB[128 * 32];
  const int t = threadIdx.x;
  const int z = blockIdx.z;
  A += z * sA; Bt += z * sB; C += z * sC;
  const long m0 = (long)blockIdx.x * 128;
  const long n0 = (long)blockIdx.y * 128;
  const int l = t & 63, w = t >> 6;
  const int wr = (w >> 1) * 64, wc = (w & 1) * 64;
  const int lr = l & 15, lg = l >> 4;

  const int c0 = t, c1 = t + 256;
  const int r0 = c0 >> 2, kc0 = (c0 & 3) * 8;
  const int r1 = c1 >> 2, kc1 = (c1 & 3) * 8;
  bf16* lA0 = lA + (w * 64) * 8;
  bf16* lA1 = lA + (256 + w * 64) * 8;
  bf16* lB0 = lB + (w * 64) * 8;
  bf16* lB1 = lB + (256 + w * 64) * 8;
  const bf16* gA0 = A + (m0 + r0) * (long)K + kc0;
  const bf16* gA1 = A + (m0 + r1) * (long)K + kc1;
  const bf16* gB0 = Bt + (n0 + r0) * (long)K + kc0;
  const bf16* gB1 = Bt + (n0 + r1) * (long)K + kc1;

  f32x4 acc[4][4] = {};
  for (int kk = 0; kk < K; kk += 32) {
    GLOAD_LDS16(gA0 + kk, lA0);
    GLOAD_LDS16(gA1 + kk, lA1);
    GLOAD_LDS16(gB0 + kk, lB0);
    GLOAD_LDS16(gB1 + kk, lB1);
    __syncthreads();
    bf16x8 af[4], bfr[4];
#pragma unroll
    for (int m = 0; m < 4; ++m)
      af[m] = *(const bf16x8*)(lA + (wr + m * 16 + lr) * 32 + lg * 8);
#pragma unroll
    for (int n = 0; n < 4; ++n)
      bfr[n] = *(const bf16x8*)(lB + (wc + n * 16 + lr) * 32 + lg * 8);
#pragma unroll
    for (int m = 0; m < 4; ++m)
#pragma unroll
      for (int n = 0; n < 4; ++n)
        acc[m][n] = __builtin_amdgcn_mfma_f32_16x16x32_bf16(af[m], bfr[n], acc[m][n], 0, 0, 0);
    __syncthreads();
  }

#pragma unroll
  for (int n = 0; n < 4; ++n) {
    const long col = n0 + wc + n * 16 + lr;
    const float bcol = bias ? bias[col] : 0.0f;
#pragma unroll
    for (int m = 0; m < 4; ++m) {
      const long rowb = m0 + wr + m * 16 + lg * 4;
#pragma unroll
      for (int r = 0; r < 4; ++r) {
        float vv = (acc[m][n][r] + bcol) * scale;
        bf16 o = (bf16)vv;
        if (outMode == 0) {
          C[(rowb + r) * (long)N + col] = o;
        } else {
          long gr = rowb + r;
          long bb = gr >> 12, ss = gr & 4095;
          C[bb * (long)(DIM * SEQ) + col * (long)SEQ + ss] = o;
        }
      }
    }
  }
}

// ---------------------------------------------------------------------------
// Main GEMM helpers (BM=128, BK=64): XOR-swizzled staging + fragment reads.
// ---------------------------------------------------------------------------
template <int BI>
__device__ __forceinline__
void stage64(const bf16* const (&gA)[4], const bf16* const (&gB)[BI],
             long kk, bf16* __restrict__ dA, bf16* __restrict__ dB, int w) {
#pragma unroll
  for (int i = 0; i < 4; ++i) GLOAD_LDS16(gA[i] + kk, dA + (i * 256 + w * 64) * 8);
#pragma unroll
  for (int i = 0; i < BI; ++i) GLOAD_LDS16(gB[i] + kk, dB + (i * 256 + w * 64) * 8);
}

template <int NFR>
__device__ __forceinline__
void compute64(const bf16* __restrict__ bufA, const bf16* __restrict__ bufB,
               const int (&offA)[4][2], const int (&offB)[NFR][2],
               f32x4 (&acc)[4][NFR]) {
#pragma unroll
  for (int ks = 0; ks < 2; ++ks) {
    bf16x8 af[4], bfn[NFR];
#pragma unroll
    for (int m = 0; m < 4; ++m) af[m] = *(const bf16x8*)(bufA + offA[m][ks]);
#pragma unroll
    for (int n = 0; n < NFR; ++n) bfn[n] = *(const bf16x8*)(bufB + offB[n][ks]);
#pragma unroll
    for (int m = 0; m < 4; ++m)
#pragma unroll
      for (int n = 0; n < NFR; ++n)
        acc[m][n] = __builtin_amdgcn_mfma_f32_16x16x32_bf16(af[m], bfn[n], acc[m][n], 0, 0, 0);
  }
}

// ---------------------------------------------------------------------------
// Main GEMM: BM=128, BK=64, BN in {64,128}, 4 waves (2x2), XOR swizzle.
// OUT 1: E = exp(acc*scale) -> bf16 C, + per-row sums via atomicAdd(rowsum).
// OUT 2: f32 out, acc * (1/rowsum[row]), written to 4 h-broadcast copies.
// DBUF 1: double-buffered LDS, 2-phase (stage next before compute current).
// ---------------------------------------------------------------------------
template <int BN, int OUT, int DBUF>
__global__ __launch_bounds__(256, 2)
void gemm64(const bf16* __restrict__ A, const bf16* __restrict__ Bt,
            void* __restrict__ Cv, float* __restrict__ rowsum,
            float scale, int N, int K, long sA, long sB, long sC) {
  constexpr int NFR = BN / 32;
  constexpr int BI = BN / 32;
  __shared__ __align__(16) bf16 lA[1 + DBUF][128 * 64];
  __shared__ __align__(16) bf16 lB[1 + DBUF][BN * 64];
  const int t = threadIdx.x;
  const int z = blockIdx.z;
  A += z * sA; Bt += z * sB;
  const long m0 = (long)blockIdx.x * 128;
  const long n0 = (long)blockIdx.y * BN;
  const int l = t & 63, w = t >> 6;
  const int wr = (w >> 1) * 64, wc = (w & 1) * (BN / 2);
  const int lr = l & 15, lg = l >> 4;

  // staging: slot s (16B units) holds row=s>>3, k-chunk (s&7)^(row&7)
  const bf16* gA[4];
  const bf16* gB[BI];
#pragma unroll
  for (int i = 0; i < 4; ++i) {
    int s = i * 256 + t, row = s >> 3, kc = (s & 7) ^ (row & 7);
    gA[i] = A + (m0 + row) * (long)K + kc * 8;
  }
#pragma unroll
  for (int i = 0; i < BI; ++i) {
    int s = i * 256 + t, row = s >> 3, kc = (s & 7) ^ (row & 7);
    gB[i] = Bt + (n0 + row) * (long)K + kc * 8;
  }

  // ds_read elem offsets: row*64 + ((ks*4+lg)^(row&7))*8 ; row&7 == lr&7
  int offA[4][2], offB[NFR][2];
#pragma unroll
  for (int m = 0; m < 4; ++m)
#pragma unroll
    for (int ks = 0; ks < 2; ++ks)
      offA[m][ks] = (wr + m * 16 + lr) * 64 + (((ks * 4 + lg) ^ (lr & 7)) * 8);
#pragma unroll
  for (int n = 0; n < NFR; ++n)
#pragma unroll
    for (int ks = 0; ks < 2; ++ks)
      offB[n][ks] = (wc + n * 16 + lr) * 64 + (((ks * 4 + lg) ^ (lr & 7)) * 8);

  f32x4 acc[4][NFR] = {};

  if constexpr (DBUF) {
    // 2-phase: issue next-tile stage BEFORE compute of current tile.
    // K must be a multiple of 128 (true for 512 and 4096).
    stage64<BI>(gA, gB, 0, lA[0], lB[0], w);
    __syncthreads();
    for (long kk = 0; kk < K; kk += 128) {
      stage64<BI>(gA, gB, kk + 64, lA[1], lB[1], w);
      compute64<NFR>(lA[0], lB[0], offA, offB, acc);
      __syncthreads();
      if (kk + 128 < K) stage64<BI>(gA, gB, kk + 128, lA[0], lB[0], w);
      compute64<NFR>(lA[1], lB[1], offA, offB, acc);
      __syncthreads();
    }
  } else {
    for (long kk = 0; kk < K; kk += 64) {
      stage64<BI>(gA, gB, kk, lA[0], lB[0], w);
      __syncthreads();
      compute64<NFR>(lA[0], lB[0], offA, offB, acc);
      __syncthreads();
    }
  }

  if constexpr (OUT == 1) {
    // E = exp(score); row-sum of bf16-rounded E accumulated to rowsum[z][row]
    bf16* C = (bf16*)Cv + z * sC;
#pragma unroll
    for (int m = 0; m < 4; ++m) {
      const long rowb = m0 + wr + m * 16 + lg * 4;
#pragma unroll
      for (int r = 0; r < 4; ++r) {
        float rsum = 0.0f;
#pragma unroll
        for (int n = 0; n < NFR; ++n) {
          const long col = n0 + wc + n * 16 + lr;
          float e = __expf(acc[m][n][r] * scale);
          bf16 eb = (bf16)e;
          C[(rowb + r) * (long)N + col] = eb;
          rsum += (float)eb;
        }
        rsum += __shfl_xor(rsum, 1);
        rsum += __shfl_xor(rsum, 2);
        rsum += __shfl_xor(rsum, 4);
        rsum += __shfl_xor(rsum, 8);
        if (lr == 0) atomicAdd(rowsum + (long)z * SEQ + rowb + r, rsum);
      }
    }
  } else {
    // O = acc / rowsum[row], broadcast to 4 heads
    float* o = (float*)Cv + z * sC;
#pragma unroll
    for (int m = 0; m < 4; ++m) {
      const long rowb = m0 + wr + m * 16 + lg * 4;
#pragma unroll
      for (int r = 0; r < 4; ++r) {
        const float inv = 1.0f / rowsum[(long)z * SEQ + rowb + r];
#pragma unroll
        for (int n = 0; n < NFR; ++n) {
          const long col = n0 + wc + n * 16 + lr;
          float vv = acc[m][n][r] * inv;
          float* p = o + (rowb + r) * (long)DIM + col;
          p[0] = vv;
          p[1L * SEQ * DIM] = vv;
          p[2L * SEQ * DIM] = vv;
          p[3L * SEQ * DIM] = vv;
        }
      }
    }
  }
}

// ---------------------------------------------------------------------------
// Host launch
// ---------------------------------------------------------------------------
extern "C" void kernel_launch(void* const* d_in, const int* in_sizes, int n_in,
                              void* d_out, int out_size, void* d_ws, size_t ws_size,
                              hipStream_t stream) {
  const float* q  = (const float*)d_in[0];
  const float* k  = (const float*)d_in[1];
  const float* v  = (const float*)d_in[2];
  const float* Wq = (const float*)d_in[3];
  const float* bq = (const float*)d_in[4];
  const float* Wv = (const float*)d_in[5];
  const float* bv = (const float*)d_in[6];
  float* outp = (float*)d_out;

  const long NQ = (long)NBATCH * SEQ * DIM;  // 4,194,304 elems
  const long NW = (long)DIM * DIM;           // 262,144
  bf16* Qbf = (bf16*)d_ws;       // scaled Q projection (bf16), [B*S, D]
  bf16* Kbf = Qbf + NQ;          // k cast (bf16), [B*S, D]
  bf16* Vt  = Kbf + NQ;          // V projection transposed, [B, D, S]
  bf16* Wqb = Vt + NQ;
  bf16* Wvb = Wqb + NW;
  bf16* Sbuf = Wvb + NW;         // E = exp(scores), bf16
  const size_t baseBytes = (size_t)((char*)Sbuf - (char*)d_ws);     // 26,214,400
  const bool batched = ws_size >= baseBytes + 2ULL * SEQ * SEQ * 2; // need +64 MiB
  bf16* qb = Sbuf;               // temporaries during cast+projections
  bf16* vb = Sbuf + NQ;
  float* rowsum = (float*)Wqb;   // 32 KB, reuses Wq-bf16 space (dead after proj)

  const float QSCALE = 0.04419417382415922f;  // 1/sqrt(512)

  cast5<<<dim3(2048), dim3(256), 0, stream>>>(q, k, v, Wq, Wv, qb, Kbf, vb, Wqb, Wvb);
  gemm_bt<<<dim3(64, 4, 1), dim3(256), 0, stream>>>(qb, Wqb, Qbf, bq, QSCALE,
                                                    512, 512, 0, 0, 0, 0);
  gemm_bt<<<dim3(64, 4, 1), dim3(256), 0, stream>>>(vb, Wvb, Vt, bv, 1.0f,
                                                    512, 512, 0, 0, 0, 1);
  const long sQK = (long)SEQ * DIM;      // 2,097,152
  const long sS  = (long)SEQ * SEQ;      // 16,777,216
  const long sO  = 4L * SEQ * DIM;       // 8,388,608 (H*S*D)
  if (batched) {
    zero_f32<<<dim3(32), dim3(256), 0, stream>>>(rowsum, NBATCH * SEQ);
    gemm64<128, 1, 0><<<dim3(32, 32, 2), dim3(256), 0, stream>>>(
        Qbf, Kbf, Sbuf, rowsum, 1.0f, 4096, 512, sQK, sQK, sS);
    gemm64<64, 2, 1><<<dim3(32, 8, 2), dim3(256), 0, stream>>>(
        Sbuf, Vt, outp, rowsum, 1.0f, 512, 4096, sS, sQK, sO);
  } else {
    for (int b = 0; b < 2; ++b) {
      zero_f32<<<dim3(16), dim3(256), 0, stream>>>(rowsum, SEQ);
      gemm64<128, 1, 0><<<dim3(32, 32, 1), dim3(256), 0, stream>>>(
          Qbf + b * sQK, Kbf + b * sQK, Sbuf, rowsum, 1.0f, 4096, 512, 0, 0, 0);
      gemm64<64, 2, 1><<<dim3(32, 8, 1), dim3(256), 0, stream>>>(
          Sbuf, Vt + b * sQK, outp + b * sO, rowsum, 1.0f, 512, 4096, 0, 0, 0);
    }
  }
}